// Round 16
// baseline (279.242 us; speedup 1.0000x reference)
//
#include <hip/hip_runtime.h>
#include <hip/hip_bf16.h>
#include <stdint.h>

#define BATCH   16384
#define EXPERTS 8
#define IN_DIM  1024
#define OUT_DIM 1024

typedef unsigned short u16;
typedef short  bf16x8 __attribute__((ext_vector_type(8)));
typedef float  f32x4  __attribute__((ext_vector_type(4)));
typedef float  f32x16 __attribute__((ext_vector_type(16)));

__device__ __forceinline__ u16 f2bf(float f) {
  uint32_t u = __float_as_uint(f);
  u += 0x7fffu + ((u >> 16) & 1u);   // RNE
  return (u16)(u >> 16);
}

#define GLDS16(g, l)                                                      \
  __builtin_amdgcn_global_load_lds(                                       \
      (const __attribute__((address_space(1))) void*)(g),                 \
      (__attribute__((address_space(3))) void*)(l), 16, 0, 0)

#define MFMA32 __builtin_amdgcn_mfma_f32_32x32x16_bf16
#define SB0 __builtin_amdgcn_sched_barrier(0)
#define LGKM(N) asm volatile("s_waitcnt lgkmcnt(" #N ")" ::: "memory")
#define VM0     asm volatile("s_waitcnt vmcnt(0)" ::: "memory")

// ---------------- kernel 1: x fp32 -> bf16 ----------------
__global__ void cvt_x(const float* __restrict__ x, u16* __restrict__ xb) {
  size_t i = ((size_t)blockIdx.x * 256 + threadIdx.x) * 4;
  float4 v = *reinterpret_cast<const float4*>(x + i);
  ushort4 o;
  o.x = f2bf(v.x); o.y = f2bf(v.y); o.z = f2bf(v.z); o.w = f2bf(v.w);
  *reinterpret_cast<ushort4*>(xb + i) = o;
}

// ------- kernel 2: W[e][i][o] fp32 -> Wbt[e][o][i] bf16 (transpose) -------
__global__ void cvt_w(const float* __restrict__ W, u16* __restrict__ wbt) {
  __shared__ u16 t[64][72];
  const int e  = blockIdx.z;
  const int i0 = blockIdx.x * 64;
  const int o0 = blockIdx.y * 64;
  const int tid = threadIdx.x;
  const int c  = (tid & 15) * 4;
  const int r_ = tid >> 4;
  const float* src = W + ((size_t)e << 20);
#pragma unroll
  for (int p = 0; p < 4; ++p) {
    int r = r_ + p * 16;
    float4 v = *reinterpret_cast<const float4*>(src + (size_t)(i0 + r) * 1024 + o0 + c);
    t[r][c + 0] = f2bf(v.x); t[r][c + 1] = f2bf(v.y);
    t[r][c + 2] = f2bf(v.z); t[r][c + 3] = f2bf(v.w);
  }
  __syncthreads();
  u16* dst = wbt + ((size_t)e << 20);
#pragma unroll
  for (int p = 0; p < 4; ++p) {
    int orow = r_ + p * 16;
    ushort4 u;
    u.x = t[c + 0][orow]; u.y = t[c + 1][orow];
    u.z = t[c + 2][orow]; u.w = t[c + 3][orow];
    *reinterpret_cast<ushort4*>(dst + (size_t)(o0 + orow) * 1024 + i0 + c) = u;
  }
}

// ------- kernel 3: Horner GEMM, r15 schedule, 32x32x16 MFMA ---------------
// BM=BN=256 BK=64, 512 thr = 8 waves (2M x 4N), wave 128x64.
// acc: f32x16[4 mb][2 nb] (128 regs).  Per K-tile: 4 kstep phases, each
// {6 b128 reads (4A+2B) issued one phase early; LGKM(6) counted; 8 MFMA
// 32x32x16}.  Same LDS bytes as 16x16 version, MFMA floor 2483->2066 cyc.
// A/B operand layout: row/col = lane&31, k = (lane>>5)*8 + j.
// C/D layout: col=lane&31, row=(reg&3)+8*(reg>>2)+4*(lane>>5).
// r15's XCD map (8 b0 x 4 n0 per XCD -> A L2-resident) + Horner rescale.
// LDS (u16 elems): A dbuf @0,@16384; B dbuf @32768,@49152; rl @65536 (4096).
__global__ __launch_bounds__(512, 2)
void zgemm(const u16* __restrict__ xb, const u16* __restrict__ wbt,
           const float* __restrict__ wts, const float* __restrict__ bias,
           float* __restrict__ y) {
  __shared__ u16 sm[69632];
  char* smb = (char*)sm;
  float* rl = (float*)(sm + 65536);          // byte 131072

  const int tid = threadIdx.x;
  const int l   = tid & 63;
  const int w   = tid >> 6;
  const int wm  = w >> 2;                    // 0..1
  const int wn  = w & 3;                     // 0..3
  const int x8  = blockIdx.x & 7;            // XCD
  const int jj  = blockIdx.x >> 3;           // 0..31
  const int b0  = ((x8 << 3) + (jj >> 2)) << 8;  // 8 A-slices/XCD (4MB, L2)
  const int n0  = (jj & 3) << 8;                 // 4 B-panels/XCD

  // ---- ratio table rl[e][256]: e<7 -> w'_e/w'_{e+1}; rl[7] = w'_7
#pragma unroll
  for (int i = 0; i < 4; ++i) {
    const int flat = tid + i * 512;
    const int e = flat & 7, r = flat >> 3;
    const float* wr = wts + (size_t)(b0 + r) * EXPERTS;
    float we = fmaxf(wr[e], 1e-20f);
    float rr = (e < 7) ? we / fmaxf(wr[e + 1], 1e-20f) : we;
    rl[e * 256 + r] = rr;
  }

  // ---- staging geometry (pre-swizzled global source, linear GLDS dest)
  const int rbl   = (w << 3) + (l >> 3);
  const int chunk = ((l & 7) ^ (l >> 3)) << 3;
  const u16* pAg = xb  + (size_t)(b0 + rbl) * IN_DIM + chunk;
  const u16* pBg = wbt + (size_t)(n0 + rbl) * 1024 + chunk;

  // ---- fragment read keys (32x32x16: row=l&31, k=(l>>5)*8+j)
  const int l31   = l & 31;
  const int kb0   = ((l >> 5) << 4) ^ ((l & 7) << 4);  // kstep s: ^ (s<<5)
  const int arow2 = (wm * 128 + l31) * 128;            // + mb*4096
  const int brow2 = (wn * 64 + l31) * 128;             // + nb*4096
  const int wlo2  = (wm << 9) + ((l >> 5) << 4);       // rl byte off

  f32x16 acc[4][2];
#pragma unroll
  for (int mb = 0; mb < 4; ++mb)
#pragma unroll
    for (int nb = 0; nb < 2; ++nb)
#pragma unroll
      for (int j = 0; j < 16; ++j) acc[mb][nb][j] = 0.f;

#define STG_A(q, dstE, kv)                                                 \
  GLDS16(pAg + (size_t)((q) * 64) * 1024 + (size_t)(kv) * 64,              \
         sm + (dstE) + (q) * 4096 + (w << 9))
#define STG_B(q, dstE, off)                                                \
  GLDS16(pBg + (off) + (size_t)((q) * 64) * 1024,                          \
         sm + (dstE) + (q) * 4096 + (w << 9))

#define RDF(AS, BS, KB, ARB, BRB)                                          \
    _Pragma("unroll")                                                      \
    for (int mb = 0; mb < 4; ++mb)                                         \
      AS[mb] = *(const bf16x8*)(smb + (ARB) + arow2 + mb * 4096 + (KB));   \
    _Pragma("unroll")                                                      \
    for (int nb = 0; nb < 2; ++nb)                                         \
      BS[nb] = *(const bf16x8*)(smb + (BRB) + brow2 + nb * 4096 + (KB));

#define MM32(AV, BV)                                                       \
  __builtin_amdgcn_s_setprio(1);                                           \
  _Pragma("unroll")                                                        \
  for (int mb = 0; mb < 4; ++mb)                                           \
    _Pragma("unroll")                                                      \
    for (int nb = 0; nb < 2; ++nb)                                         \
      acc[mb][nb] = MFMA32(AV[mb], BV[nb], acc[mb][nb], 0, 0, 0);          \
  __builtin_amdgcn_s_setprio(0);

  // ---- prologue: tile 0 -> parity-0; drain; publish
  STG_A(0, 0, 0); STG_A(1, 0, 0); STG_A(2, 0, 0); STG_A(3, 0, 0);
  STG_B(0, 32768, 0); STG_B(1, 32768, 0); STG_B(2, 32768, 0); STG_B(3, 32768, 0);
  VM0;
  LGKM(0);                                   // rl ds_writes drained
  __builtin_amdgcn_s_barrier();

// BODY: TT tile-idx expr (compile-time parity); read/stage bases as r15.
#define BODY(TT, ARB, BRB, AWE, BWE)                                       \
  {                                                                        \
    const int tn  = ((TT) + 1) & 127;                                      \
    const int e1  = tn >> 4, k1 = tn & 15;                                 \
    const size_t boffg = (size_t)e1 * 1048576 + (size_t)k1 * 64;           \
    bf16x8 A0[4], B0[2], A1[4], B1[2], A2[4], B2[2], A3[4], B3[2];         \
    RDF(A0, B0, kb0,      ARB, BRB)                                        \
    RDF(A1, B1, kb0 ^ 32, ARB, BRB)                                        \
    STG_A(0, AWE, k1); STG_A(1, AWE, k1); STG_A(2, AWE, k1); STG_A(3, AWE, k1); \
    STG_B(0, BWE, boffg); STG_B(1, BWE, boffg);                            \
    STG_B(2, BWE, boffg); STG_B(3, BWE, boffg);                            \
    LGKM(6); SB0;                          /* F0 done (F1 in flight) */    \
    RDF(A2, B2, kb0 ^ 64, ARB, BRB)                                        \
    MM32(A0, B0)                           /* P0 */                        \
    LGKM(6); SB0;                          /* F1 done */                   \
    RDF(A3, B3, kb0 ^ 96, ARB, BRB)                                        \
    MM32(A1, B1)                           /* P1 */                        \
    LGKM(6); SB0;                          /* F2 done */                   \
    MM32(A2, B2)                           /* P2 */                        \
    LGKM(0); SB0;                          /* F3 done */                   \
    MM32(A3, B3)                           /* P3 */                        \
    VM0;                                   /* t+1 staging landed */        \
    __builtin_amdgcn_s_barrier();          /* publish (only barrier) */    \
    if (((TT) & 15) == 15 && (TT) != 127) {                                \
      const int e = (TT) >> 4;                                             \
      f32x4 rv[4][4];                                                      \
      _Pragma("unroll")                                                    \
      for (int mb = 0; mb < 4; ++mb)                                       \
        _Pragma("unroll")                                                  \
        for (int q = 0; q < 4; ++q)                                        \
          rv[mb][q] = *(const f32x4*)(smb + 131072 + e * 1024 + wlo2       \
                                      + mb * 128 + q * 32);                \
      LGKM(0); SB0;                                                        \
      _Pragma("unroll")                                                    \
      for (int mb = 0; mb < 4; ++mb)                                       \
        _Pragma("unroll")                                                  \
        for (int nb = 0; nb < 2; ++nb)                                     \
          _Pragma("unroll")                                                \
          for (int q = 0; q < 4; ++q)                                      \
            _Pragma("unroll")                                              \
            for (int j = 0; j < 4; ++j)                                    \
              acc[mb][nb][4 * q + j] *= rv[mb][q][j];                      \
    }                                                                      \
  }

#pragma unroll 1
  for (int t = 0; t < 128; t += 2) {
    BODY(t,     0,     65536, 16384, 49152)   // read parity0, stage parity1
    BODY(t + 1, 32768, 98304, 0,     32768)   // read parity1, stage parity0
  }
  VM0; LGKM(0);

  // ---- epilogue: y = w'_7 * acc + sum_e w_e * bias_e
  float bv[2][8];
#pragma unroll
  for (int nb = 0; nb < 2; ++nb) {
    const int c = n0 + wn * 64 + nb * 32 + l31;
#pragma unroll
    for (int ee = 0; ee < 8; ++ee) bv[nb][ee] = bias[ee * OUT_DIM + c];
  }
#pragma unroll
  for (int mb = 0; mb < 4; ++mb) {
    f32x4 rv7[4];
#pragma unroll
    for (int q = 0; q < 4; ++q)
      rv7[q] = *(const f32x4*)(smb + 131072 + 7 * 1024 + wlo2 + mb * 128 + q * 32);
#pragma unroll
    for (int q = 0; q < 4; ++q) {
      const int rbase = b0 + wm * 128 + mb * 32 + q * 8 + ((l >> 5) << 2);
#pragma unroll
      for (int j = 0; j < 4; ++j) {
        const int row = rbase + j;
        float4 wl4 = *reinterpret_cast<const float4*>(wts + (size_t)row * 8);
        float4 wh4 = *reinterpret_cast<const float4*>(wts + (size_t)row * 8 + 4);
        float w8[8] = {wl4.x, wl4.y, wl4.z, wl4.w, wh4.x, wh4.y, wh4.z, wh4.w};
#pragma unroll
        for (int nb = 0; nb < 2; ++nb) {
          const int c = n0 + wn * 64 + nb * 32 + l31;
          float v = acc[mb][nb][4 * q + j] * rv7[q][j];
#pragma unroll
          for (int ee = 0; ee < 8; ++ee) v += w8[ee] * bv[nb][ee];
          y[(size_t)row * OUT_DIM + c] = v;
        }
      }
    }
  }
}

extern "C" void kernel_launch(void* const* d_in, const int* in_sizes, int n_in,
                              void* d_out, int out_size, void* d_ws, size_t ws_size,
                              hipStream_t stream) {
  const float* x    = (const float*)d_in[0];
  const float* wts  = (const float*)d_in[1];
  const float* W    = (const float*)d_in[2];
  const float* bias = (const float*)d_in[3];
  float* y = (float*)d_out;

  const size_t xb_elems = (size_t)BATCH * IN_DIM;                 // 32 MB bf16
  const size_t wb_elems = (size_t)EXPERTS * IN_DIM * OUT_DIM;     // 16 MB bf16
  if (ws_size < (xb_elems + wb_elems) * sizeof(u16)) return;      // loud failure
  u16* xb  = (u16*)d_ws;
  u16* wbt = xb + xb_elems;

  cvt_x<<<(BATCH * IN_DIM) / (4 * 256), 256, 0, stream>>>(x, xb);
  cvt_w<<<dim3(IN_DIM / 64, OUT_DIM / 64, EXPERTS), 256, 0, stream>>>(W, wbt);
  zgemm<<<dim3(256), 512, 0, stream>>>(xb, wbt, wts, bias, y);
}

// Round 17
// 246.615 us; speedup vs baseline: 1.1323x; 1.1323x over previous
//
#include <hip/hip_runtime.h>
#include <hip/hip_bf16.h>
#include <stdint.h>

#define BATCH   16384
#define EXPERTS 8
#define IN_DIM  1024
#define OUT_DIM 1024

typedef unsigned short u16;
typedef short  bf16x8 __attribute__((ext_vector_type(8)));
typedef float  f32x4  __attribute__((ext_vector_type(4)));

__device__ __forceinline__ u16 f2bf(float f) {
  uint32_t u = __float_as_uint(f);
  u += 0x7fffu + ((u >> 16) & 1u);   // RNE
  return (u16)(u >> 16);
}

#define GLDS16(g, l)                                                      \
  __builtin_amdgcn_global_load_lds(                                       \
      (const __attribute__((address_space(1))) void*)(g),                 \
      (__attribute__((address_space(3))) void*)(l), 16, 0, 0)

#define MFMA_BF16 __builtin_amdgcn_mfma_f32_16x16x32_bf16
#define SB0 __builtin_amdgcn_sched_barrier(0)
#define LGKM(N) asm volatile("s_waitcnt lgkmcnt(" #N ")" ::: "memory")
#define VM0     asm volatile("s_waitcnt vmcnt(0)" ::: "memory")

// ---------------- kernel 1: x fp32 -> bf16 ----------------
__global__ void cvt_x(const float* __restrict__ x, u16* __restrict__ xb) {
  size_t i = ((size_t)blockIdx.x * 256 + threadIdx.x) * 4;
  float4 v = *reinterpret_cast<const float4*>(x + i);
  ushort4 o;
  o.x = f2bf(v.x); o.y = f2bf(v.y); o.z = f2bf(v.z); o.w = f2bf(v.w);
  *reinterpret_cast<ushort4*>(xb + i) = o;
}

// ------- kernel 2: W[e][i][o] fp32 -> Wbt[e][o][i] bf16 (transpose) -------
__global__ void cvt_w(const float* __restrict__ W, u16* __restrict__ wbt) {
  __shared__ u16 t[64][72];
  const int e  = blockIdx.z;
  const int i0 = blockIdx.x * 64;
  const int o0 = blockIdx.y * 64;
  const int tid = threadIdx.x;
  const int c  = (tid & 15) * 4;
  const int r_ = tid >> 4;
  const float* src = W + ((size_t)e << 20);
#pragma unroll
  for (int p = 0; p < 4; ++p) {
    int r = r_ + p * 16;
    float4 v = *reinterpret_cast<const float4*>(src + (size_t)(i0 + r) * 1024 + o0 + c);
    t[r][c + 0] = f2bf(v.x); t[r][c + 1] = f2bf(v.y);
    t[r][c + 2] = f2bf(v.z); t[r][c + 3] = f2bf(v.w);
  }
  __syncthreads();
  u16* dst = wbt + ((size_t)e << 20);
#pragma unroll
  for (int p = 0; p < 4; ++p) {
    int orow = r_ + p * 16;
    ushort4 u;
    u.x = t[c + 0][orow]; u.y = t[c + 1][orow];
    u.z = t[c + 2][orow]; u.w = t[c + 3][orow];
    *reinterpret_cast<ushort4*>(dst + (size_t)(o0 + orow) * 1024 + i0 + c) = u;
  }
}

// ---------------- kernel 3: Horner GEMM, r15 schedule + wave kf-stagger ---
// BM=BN=256 BK=64, 512 thr = 8 waves (2M x 4N), wave 128x64, acc 128 VGPR.
// r15 free-running tile (best measured: 225us zgemm / 56.8% MfmaUtil):
//   top: F0(8)+F1(4) reads + 8 GLDS (t+1, other parity)
//   LGKM(4)->F0 | F2 under P0 | LGKM(8)->F1 | F3 under P1 |
//   LGKM(4)->F2 | P2 | LGKM(0)->F3 | P3 | VM0 | barrier | [rescale 7x]
// NEW: wave-parity kf stagger (kbw = kb0 ^ ((w&1)<<6)): even waves do
// kf0->kf1, odd waves kf1->kf0.  Accumulation over kf is commutative within
// a tile; both kf halves read the same published buffer -> ledger identical.
// At any instant half the SIMD's waves read while half MFMA -> overlap.
// XCD map: 8 b0-slices x 4 n0-panels per XCD -> A L2-resident (FETCH 199MB).
// LDS (u16 elems): A dbuf @0,@16384; B dbuf @32768,@49152; rl @65536 (4096).
__global__ __launch_bounds__(512, 2)
void zgemm(const u16* __restrict__ xb, const u16* __restrict__ wbt,
           const float* __restrict__ wts, const float* __restrict__ bias,
           float* __restrict__ y) {
  __shared__ u16 sm[69632];
  char* smb = (char*)sm;
  float* rl = (float*)(sm + 65536);          // byte 131072

  const int tid = threadIdx.x;
  const int l   = tid & 63;
  const int w   = tid >> 6;
  const int wm  = w >> 2;                    // 0..1
  const int wn  = w & 3;                     // 0..3
  const int x8  = blockIdx.x & 7;            // XCD
  const int jj  = blockIdx.x >> 3;           // 0..31
  const int b0  = ((x8 << 3) + (jj >> 2)) << 8;  // 8 A-slices/XCD (4MB, L2)
  const int n0  = (jj & 3) << 8;                 // 4 B-panels/XCD

  // ---- ratio table rl[e][256]: e<7 -> w'_e/w'_{e+1}; rl[7] = w'_7
#pragma unroll
  for (int i = 0; i < 4; ++i) {
    const int flat = tid + i * 512;
    const int e = flat & 7, r = flat >> 3;
    const float* wr = wts + (size_t)(b0 + r) * EXPERTS;
    float we = fmaxf(wr[e], 1e-20f);
    float rr = (e < 7) ? we / fmaxf(wr[e + 1], 1e-20f) : we;
    rl[e * 256 + r] = rr;
  }

  // ---- staging geometry (pre-swizzled global source, linear GLDS dest)
  const int rbl   = (w << 3) + (l >> 3);
  const int chunk = ((l & 7) ^ (l >> 3)) << 3;
  const u16* pAg = xb  + (size_t)(b0 + rbl) * IN_DIM + chunk;
  const u16* pBg = wbt + (size_t)(n0 + rbl) * 1024 + chunk;

  // ---- fragment read keys (kf staggered by wave parity)
  const int l15  = l & 15;
  const int kbw  = ((((l >> 4) << 4)) ^ ((l & 7) << 4)) ^ ((w & 1) << 6);
  const int arow = (wm * 128 + l15) * 128;               // + m*2048
  const int brow = (wn * 64 + l15) * 128;                // + n*2048
  const int wlo  = (wm << 9) + ((l >> 4) << 4);          // rl byte off + m*64

  f32x4 acc[8][4];
#pragma unroll
  for (int m = 0; m < 8; ++m)
#pragma unroll
    for (int n = 0; n < 4; ++n) acc[m][n] = (f32x4){0.f, 0.f, 0.f, 0.f};

#define STG_A(q, dstE, kv)                                                 \
  GLDS16(pAg + (size_t)((q) * 64) * 1024 + (size_t)(kv) * 64,              \
         sm + (dstE) + (q) * 4096 + (w << 9))
#define STG_B(q, dstE, off)                                                \
  GLDS16(pBg + (off) + (size_t)((q) * 64) * 1024,                          \
         sm + (dstE) + (q) * 4096 + (w << 9))

#define MM(AV, BV, MB)                                                     \
  __builtin_amdgcn_s_setprio(1);                                           \
  _Pragma("unroll")                                                        \
  for (int m = 0; m < 4; ++m)                                              \
    _Pragma("unroll")                                                      \
    for (int n = 0; n < 4; ++n)                                            \
      acc[(MB) + m][n] = MFMA_BF16(AV[m], BV[n], acc[(MB) + m][n], 0, 0, 0); \
  __builtin_amdgcn_s_setprio(0);

  // ---- prologue: tile 0 -> parity-0; drain; publish
  STG_A(0, 0, 0); STG_A(1, 0, 0); STG_A(2, 0, 0); STG_A(3, 0, 0);
  STG_B(0, 32768, 0); STG_B(1, 32768, 0); STG_B(2, 32768, 0); STG_B(3, 32768, 0);
  VM0;
  LGKM(0);                                   // rl ds_writes drained
  __builtin_amdgcn_s_barrier();

// BODY: TT tile-idx expr (parity known); ARB/BRB read bases (bytes);
// AWE/BWE stage bases (elems).  Exact r15 per-tile sequence, kbw stagger.
#define BODY(TT, ARB, BRB, AWE, BWE)                                       \
  {                                                                        \
    const int tn  = ((TT) + 1) & 127;                                      \
    const int e1  = tn >> 4, k1 = tn & 15;                                 \
    const size_t boffg = (size_t)e1 * 1048576 + (size_t)k1 * 64;           \
    bf16x8 a0[4], b0v[4], a1[4], a2v[4], b1v[4], a3[4];                    \
    _Pragma("unroll")                                                      \
    for (int m = 0; m < 4; ++m)                                            \
      a0[m] = *(const bf16x8*)(smb + (ARB) + arow + m * 2048 + kbw);       \
    _Pragma("unroll")                                                      \
    for (int n = 0; n < 4; ++n)                                            \
      b0v[n] = *(const bf16x8*)(smb + (BRB) + brow + n * 2048 + kbw);      \
    _Pragma("unroll")                                                      \
    for (int m = 0; m < 4; ++m)                                            \
      a1[m] = *(const bf16x8*)(smb + (ARB) + arow + (m + 4) * 2048 + kbw); \
    STG_A(0, AWE, k1); STG_A(1, AWE, k1); STG_A(2, AWE, k1); STG_A(3, AWE, k1); \
    STG_B(0, BWE, boffg); STG_B(1, BWE, boffg);                            \
    STG_B(2, BWE, boffg); STG_B(3, BWE, boffg);                            \
    LGKM(4); SB0;                          /* F0 done (F1 in flight) */    \
    _Pragma("unroll")                                                      \
    for (int m = 0; m < 4; ++m)                                            \
      a2v[m] = *(const bf16x8*)(smb + (ARB) + arow + m * 2048 + (kbw ^ 64)); \
    _Pragma("unroll")                                                      \
    for (int n = 0; n < 4; ++n)                                            \
      b1v[n] = *(const bf16x8*)(smb + (BRB) + brow + n * 2048 + (kbw ^ 64)); \
    MM(a0, b0v, 0)                         /* P0 */                        \
    LGKM(8); SB0;                          /* F1 done */                   \
    _Pragma("unroll")                                                      \
    for (int m = 0; m < 4; ++m)                                            \
      a3[m] = *(const bf16x8*)(smb + (ARB) + arow + (m + 4) * 2048 + (kbw ^ 64)); \
    MM(a1, b0v, 4)                         /* P1 */                        \
    LGKM(4); SB0;                          /* F2 done */                   \
    MM(a2v, b1v, 0)                        /* P2 */                        \
    LGKM(0); SB0;                          /* F3 done */                   \
    MM(a3, b1v, 4)                         /* P3 */                        \
    VM0;                                   /* t+1 staging landed */        \
    __builtin_amdgcn_s_barrier();          /* publish (only barrier) */    \
    if (((TT) & 15) == 15 && (TT) != 127) {                                \
      const int e = (TT) >> 4;                                             \
      f32x4 rv[8];                                                         \
      _Pragma("unroll")                                                    \
      for (int m = 0; m < 8; ++m)                                          \
        rv[m] = *(const f32x4*)(smb + 131072 + e * 1024 + wlo + m * 64);   \
      LGKM(0); SB0;                                                        \
      _Pragma("unroll")                                                    \
      for (int m = 0; m < 8; ++m)                                          \
        _Pragma("unroll")                                                  \
        for (int n = 0; n < 4; ++n) acc[m][n] *= rv[m];                    \
    }                                                                      \
  }

#pragma unroll 1
  for (int t = 0; t < 128; t += 2) {
    BODY(t,     0,     65536, 16384, 49152)   // read parity0, stage parity1
    BODY(t + 1, 32768, 98304, 0,     32768)   // read parity1, stage parity0
  }
  VM0; LGKM(0);

  // ---- epilogue: y = w'_7 * acc + sum_e w_e * bias_e
  float bv[4][8];
#pragma unroll
  for (int n = 0; n < 4; ++n) {
    const int c = n0 + wn * 64 + n * 16 + l15;
#pragma unroll
    for (int ee = 0; ee < 8; ++ee) bv[n][ee] = bias[ee * OUT_DIM + c];
  }
#pragma unroll
  for (int m = 0; m < 8; ++m) {
    const f32x4 rv7 = *(const f32x4*)(smb + 131072 + 7 * 1024 + wlo + m * 64);
    const int r0 = b0 + wm * 128 + m * 16 + ((l >> 4) << 2);
#pragma unroll
    for (int j = 0; j < 4; ++j) {
      const float* wr = wts + (size_t)(r0 + j) * EXPERTS;
      float w8[8];
#pragma unroll
      for (int ee = 0; ee < 8; ++ee) w8[ee] = wr[ee];
#pragma unroll
      for (int n = 0; n < 4; ++n) {
        const int c = n0 + wn * 64 + n * 16 + l15;
        float v = acc[m][n][j] * rv7[j];
#pragma unroll
        for (int ee = 0; ee < 8; ++ee) v += w8[ee] * bv[n][ee];
        y[(size_t)(r0 + j) * OUT_DIM + c] = v;
      }
    }
  }
}

extern "C" void kernel_launch(void* const* d_in, const int* in_sizes, int n_in,
                              void* d_out, int out_size, void* d_ws, size_t ws_size,
                              hipStream_t stream) {
  const float* x    = (const float*)d_in[0];
  const float* wts  = (const float*)d_in[1];
  const float* W    = (const float*)d_in[2];
  const float* bias = (const float*)d_in[3];
  float* y = (float*)d_out;

  const size_t xb_elems = (size_t)BATCH * IN_DIM;                 // 32 MB bf16
  const size_t wb_elems = (size_t)EXPERTS * IN_DIM * OUT_DIM;     // 16 MB bf16
  if (ws_size < (xb_elems + wb_elems) * sizeof(u16)) return;      // loud failure
  u16* xb  = (u16*)d_ws;
  u16* wbt = xb + xb_elems;

  cvt_x<<<(BATCH * IN_DIM) / (4 * 256), 256, 0, stream>>>(x, xb);
  cvt_w<<<dim3(IN_DIM / 64, OUT_DIM / 64, EXPERTS), 256, 0, stream>>>(W, wbt);
  zgemm<<<dim3(256), 512, 0, stream>>>(xb, wbt, wts, bias, y);
}